// Round 4
// baseline (428.348 us; speedup 1.0000x reference)
//
#include <hip/hip_runtime.h>

#define B 16
#define S 2048
#define D 256

typedef float fx4 __attribute__((ext_vector_type(4)));
typedef int   ix4 __attribute__((ext_vector_type(4)));

// Kernel 1: per-row projections. One 64-lane wave per (b,s) row.
// lane l handles d = 4l..4l+3 (64*4 = 256 = D exactly).
__global__ __launch_bounds__(256) void rowdot_kernel(
    const float* __restrict__ x,     // [B*S, D]
    const float* __restrict__ W,     // [2*D]
    const float* __restrict__ bptr,  // [1]
    float* __restrict__ si,          // [B*S]  (stores si + b)
    float* __restrict__ sj)          // [B*S]
{
    const int wave = (blockIdx.x * blockDim.x + threadIdx.x) >> 6;
    const int lane = threadIdx.x & 63;
    if (wave >= B * S) return;

    const fx4 xv = *reinterpret_cast<const fx4*>(x + (size_t)wave * D + lane * 4);
    const fx4 wi = *reinterpret_cast<const fx4*>(W + lane * 4);
    const fx4 wj = *reinterpret_cast<const fx4*>(W + D + lane * 4);

    float a = xv.x * wi.x + xv.y * wi.y + xv.z * wi.z + xv.w * wi.w;
    float c = xv.x * wj.x + xv.y * wj.y + xv.z * wj.z + xv.w * wj.w;

    #pragma unroll
    for (int m = 32; m >= 1; m >>= 1) {
        a += __shfl_xor(a, m, 64);
        c += __shfl_xor(c, m, 64);
    }
    if (lane == 0) {
        si[wave] = a + bptr[0];   // fold bias into si once
        sj[wave] = c;
    }
}

__device__ __forceinline__ float blend_one(float arg, float adjv, int m) {
    // sigmoid(arg) = 1 / (1 + 2^(-arg*log2(e))) via HW v_exp_f32 / v_rcp_f32
    const float e   = __builtin_amdgcn_exp2f(-1.44269504088896f * arg);
    const float sig = __builtin_amdgcn_rcpf(1.0f + e);
    const float v   = 0.6f * sig + 0.4f * adjv;
    return m ? v : 1e-9f;
}

// Kernel 2: one block per FOUR consecutive (b,i) rows (same batch: groups are
// 4-aligned, batches are 2048 rows). All adj loads for the group's unmasked
// rows issue upfront (8 independent 16B loads/thread = 4x deeper MLP, reads
// clustered in 32KB bursts); sj/mask_j loads amortized over 4 rows.
// Per-row mask_i==0 elision preserved (block-uniform branch).
__global__ __launch_bounds__(256) void fuse_kernel(
    const float* __restrict__ adj,   // [B, S, S]
    const int*   __restrict__ mask,  // [B, S]
    const float* __restrict__ si,    // [B*S] (si + b)
    const float* __restrict__ sj,    // [B*S]
    float* __restrict__ out)         // [B, S, S]
{
    const int g    = blockIdx.x;            // 0 .. B*S/4-1
    const int row0 = g << 2;
    const int bb   = row0 >> 11;            // batch
    const int t    = threadIdx.x;
    const int j0   = t << 2;                // 0..1020 step 4; +1024 for k=1

    const ix4 mi4 = *reinterpret_cast<const ix4*>(mask + row0);  // uniform
    const fx4 si4 = *reinterpret_cast<const fx4*>(si + row0);    // uniform
    const int   mi_[4] = {mi4.x, mi4.y, mi4.z, mi4.w};
    const float si_[4] = {si4.x, si4.y, si4.z, si4.w};

    const long long base0 = (long long)row0 << 11;

    // Phase 1: all adj loads upfront (unmasked rows only).
    fx4 a[4][2];
    #pragma unroll
    for (int r = 0; r < 4; ++r) {
        if (mi_[r]) {
            const long long rb = base0 + ((long long)r << 11);
            a[r][0] = __builtin_nontemporal_load(
                reinterpret_cast<const fx4*>(adj + rb + j0));
            a[r][1] = __builtin_nontemporal_load(
                reinterpret_cast<const fx4*>(adj + rb + j0 + 1024));
        }
    }

    // j-slice data (L2-resident, shared across the 4 rows).
    const int jb = bb << 11;
    fx4 sjv[2]; ix4 mjv[2];
    sjv[0] = *reinterpret_cast<const fx4*>(sj + jb + j0);
    sjv[1] = *reinterpret_cast<const fx4*>(sj + jb + j0 + 1024);
    mjv[0] = *reinterpret_cast<const ix4*>(mask + jb + j0);
    mjv[1] = *reinterpret_cast<const ix4*>(mask + jb + j0 + 1024);

    const fx4 fill = {1e-9f, 1e-9f, 1e-9f, 1e-9f};

    // Phase 2: compute + store.
    #pragma unroll
    for (int r = 0; r < 4; ++r) {
        const long long rb = base0 + ((long long)r << 11);
        if (mi_[r]) {
            const float s_i = si_[r];
            #pragma unroll
            for (int k = 0; k < 2; ++k) {
                fx4 o;
                o.x = blend_one(s_i + sjv[k].x, a[r][k].x, mjv[k].x);
                o.y = blend_one(s_i + sjv[k].y, a[r][k].y, mjv[k].y);
                o.z = blend_one(s_i + sjv[k].z, a[r][k].z, mjv[k].z);
                o.w = blend_one(s_i + sjv[k].w, a[r][k].w, mjv[k].w);
                __builtin_nontemporal_store(o,
                    reinterpret_cast<fx4*>(out + rb + j0 + (k << 10)));
            }
        } else {
            __builtin_nontemporal_store(fill,
                reinterpret_cast<fx4*>(out + rb + j0));
            __builtin_nontemporal_store(fill,
                reinterpret_cast<fx4*>(out + rb + j0 + 1024));
        }
    }
}

extern "C" void kernel_launch(void* const* d_in, const int* in_sizes, int n_in,
                              void* d_out, int out_size, void* d_ws, size_t ws_size,
                              hipStream_t stream) {
    const float* x    = (const float*)d_in[0];
    const float* adj  = (const float*)d_in[1];
    const int*   mask = (const int*)d_in[2];
    const float* W    = (const float*)d_in[3];
    const float* bptr = (const float*)d_in[4];
    float* out = (float*)d_out;

    float* si = (float*)d_ws;           // B*S floats
    float* sj = si + (size_t)B * S;     // B*S floats  (256 KB total << ws)

    // Kernel 1: one wave per row, 4 waves per block -> B*S/4 blocks.
    rowdot_kernel<<<(B * S) / 4, 256, 0, stream>>>(x, W, bptr, si, sj);

    // Kernel 2: one block per 4 output rows.
    fuse_kernel<<<(B * S) / 4, 256, 0, stream>>>(adj, mask, si, sj, out);
}